// Round 11
// baseline (929.419 us; speedup 1.0000x reference)
//
#include <hip/hip_runtime.h>
#include <math.h>

#define NDIM 64
typedef float f32x2 __attribute__((ext_vector_type(2)));

#define MEMFENCE() asm volatile("" ::: "memory")

// Broadcast lane `lane`'s value to all lanes (uniform / SGPR).
__device__ __forceinline__ float rl(float v, int lane) {
    return __uint_as_float((unsigned)__builtin_amdgcn_readlane(__float_as_uint(v), lane));
}

// DPP add step with compile-time control/row mask.
template<int CTRL, int ROW_MASK>
__device__ __forceinline__ float dpp_add(float x) {
    int m = __builtin_amdgcn_update_dpp(0, __float_as_int(x), CTRL, ROW_MASK, 0xf, true);
    return x + __int_as_float(m);
}
// Full-wave64 sum via DPP; total lands in lane 63, broadcast via readlane.
__device__ __forceinline__ float wave_sum(float x) {
    x = dpp_add<0x111, 0xf>(x);   // row_shr:1
    x = dpp_add<0x112, 0xf>(x);   // row_shr:2
    x = dpp_add<0x114, 0xf>(x);   // row_shr:4
    x = dpp_add<0x118, 0xf>(x);   // row_shr:8
    x = dpp_add<0x142, 0xa>(x);   // row_bcast:15 -> rows 1,3
    x = dpp_add<0x143, 0xc>(x);   // row_bcast:31 -> row 3
    return rl(x, 63);
}
__device__ __forceinline__ float wave_min(float v) {
    #pragma unroll
    for (int off = 1; off < 64; off <<= 1) v = fminf(v, __shfl_xor(v, off, 64));
    return v;
}
__device__ __forceinline__ float wave_max(float v) {
    #pragma unroll
    for (int off = 1; off < 64; off <<= 1) v = fmaxf(v, __shfl_xor(v, off, 64));
    return v;
}

// Householder iterations k in [K0, K1); K0 multiple of 8. Pipelined: s2/a1 of
// iteration k+1 are computed from the closed-form next column BEFORE the
// rank-2 update loop, so the DPP reduction latency hides under the update's
// issue stream. Column broadcast buffers ping-pong by k parity (the update
// still reads the old column). Single-wave DS ordering; no barriers.
template<int K0, int K1>
__device__ __forceinline__ void tri_chunk(f32x2 (&r2)[32], float& colreg,
                                          float& s2, float& a1,
                                          float& dval, float& e2val, const int t,
                                          float4* ab0, float4* ab1, float4* ub4) {
    float* ubp = (float*)ub4;
    constexpr int Q0 = K0 / 4;
    #pragma unroll 1
    for (int k = K0; k < K1; ++k) {
        const float4* aRd = (k & 1) ? ab1 : ab0;
        float* aWr = (k & 1) ? (float*)ab0 : (float*)ab1;
        float akt = (t > k) ? colreg : 0.0f;
        float sigma = sqrtf(s2);
        float alpha = (a1 >= 0.0f) ? -sigma : sigma;   // e[k]=alpha, e[k]^2=s2
        e2val = (t == k) ? s2 : e2val;
        float vt = akt - ((t == k + 1) ? alpha : 0.0f);
        float vtv = 2.0f * (s2 - alpha * a1);
        float beta = (vtv > 1e-30f) ? 2.0f * __builtin_amdgcn_rcpf(vtv) : 0.0f;

        // pre-update r_t[k+1] (static window select)
        float pre_col = colreg;
        #pragma unroll
        for (int j = K0 + 1; j <= K1; ++j)
            if (j == k + 1) pre_col = (j & 1) ? r2[j >> 1].y : r2[j >> 1].x;

        // u_t = sum_j a[j]*r_t[j] - alpha*r_t[k+1]; two accumulation chains
        f32x2 acc0 = {0.0f, 0.0f}, acc1 = {0.0f, 0.0f};
        #pragma unroll
        for (int q = Q0; q < 16; ++q) {
            float4 aq = aRd[q];
            f32x2 a01; a01.x = aq.x; a01.y = aq.y;
            f32x2 a23; a23.x = aq.z; a23.y = aq.w;
            acc0 = __builtin_elementwise_fma(r2[2 * q],     a01, acc0);
            acc1 = __builtin_elementwise_fma(r2[2 * q + 1], a23, acc1);
        }
        float ut = (acc0.x + acc0.y) + (acc1.x + acc1.y) - alpha * pre_col;
        float vtu = wave_sum(vt * ut);
        float u_store = (t > k) ? ut : 0.0f;
        ubp[t] = u_store;
        MEMFENCE();
        float c  = 0.5f * beta * beta * vtu;
        float p1 = vt * beta;
        float p2 = (t > k) ? (beta * ut - 2.0f * c * vt) : 0.0f;
        float uk1 = rl(u_store, k + 1);
        float ncol = pre_col - p1 * uk1 - p2 * a1 + alpha * p2;  // exact r_t[k+1]'

        // ---- pipeline: publish next column, start next s2/a1 NOW ----
        float akt_next = (t > k + 1) ? ncol : 0.0f;
        aWr[t] = akt_next;
        MEMFENCE();
        s2 = wave_sum(akt_next * akt_next);    // latency hidden by update below
        a1 = rl(akt_next, k + 2);

        // rank-2 update: r[j] -= p1*u[j] + p2*a[j] (reads OLD column buffer)
        f32x2 np1; np1.x = -p1; np1.y = -p1;
        f32x2 np2; np2.x = -p2; np2.y = -p2;
        #pragma unroll
        for (int q = Q0; q < 16; ++q) {
            float4 uq = ub4[q];
            float4 aq = aRd[q];
            f32x2 u01; u01.x = uq.x; u01.y = uq.y;
            f32x2 u23; u23.x = uq.z; u23.y = uq.w;
            f32x2 a01; a01.x = aq.x; a01.y = aq.y;
            f32x2 a23; a23.x = aq.z; a23.y = aq.w;
            r2[2 * q]     = __builtin_elementwise_fma(np1, u01,
                            __builtin_elementwise_fma(np2, a01, r2[2 * q]));
            r2[2 * q + 1] = __builtin_elementwise_fma(np1, u23,
                            __builtin_elementwise_fma(np2, a23, r2[2 * q + 1]));
        }
        // exact element k+1 (delta term) via the closed form
        #pragma unroll
        for (int j = K0 + 1; j <= K1; ++j) {
            if (j == k + 1) {
                if (j & 1) r2[j >> 1].y = ncol; else r2[j >> 1].x = ncol;
            }
        }
        colreg = ncol;
        dval = (t == k + 1) ? ncol : dval;     // d[k+1] final after iter k
    }
}

// One-time prep: Sa = 0.5(A+A^T), Bh = 0.5B, Bt = 0.5B^T, Ch = 0.5C, Ct = 0.5C^T.
__global__ __launch_bounds__(64)
void prep_kernel(const float* __restrict__ A, const float* __restrict__ B,
                 const float* __restrict__ C, float* __restrict__ ws) {
    const int t = threadIdx.x;
    float* Sa = ws;
    float* Bh = ws + 4096;
    float* Bt = ws + 8192;
    float* Ch = ws + 12288;
    float* Ct = ws + 16384;
    for (int j = 0; j < NDIM; ++j) {
        Sa[t * NDIM + j] = 0.5f * (A[t * NDIM + j] + A[j * NDIM + t]);
        Bh[t * NDIM + j] = 0.5f * B[t * NDIM + j];
        Bt[t * NDIM + j] = 0.5f * B[j * NDIM + t];
        Ch[t * NDIM + j] = 0.5f * C[t * NDIM + j];
        Ct[t * NDIM + j] = 0.5f * C[j * NDIM + t];
    }
}

// One wave (64 threads) per block = one matrix; flexible CU packing.
__global__ __launch_bounds__(64, 2)
void bispec_eig_kernel(const float* __restrict__ x, const float* __restrict__ y,
                       const float* __restrict__ ws, const int* __restrict__ idxp,
                       float* __restrict__ out, int batch) {
    const int t = threadIdx.x;
    const int b = blockIdx.x;
    if (b >= batch) return;

    __shared__ float4 ab0s[16];
    __shared__ float4 ab1s[16];
    __shared__ float4 ub4s[16];
    __shared__ float2 des[64];
    float4* ab0 = ab0s;
    float4* ab1 = ab1s;
    float4* ub4 = ub4s;

    const float xi = x[b * NDIM + t];
    const float yi = y[b * NDIM + t];
    ((float*)ab0)[t] = xi;            // x broadcast (reused for column later)
    ((float*)ub4)[t] = yi;            // y broadcast (reused for u later)
    MEMFENCE();

    const float4* Sa4 = (const float4*)(ws + t * NDIM);
    const float4* Bh4 = (const float4*)(ws + 4096 + t * NDIM);
    const float4* Bt4 = (const float4*)(ws + 8192 + t * NDIM);
    const float4* Ch4 = (const float4*)(ws + 12288 + t * NDIM);
    const float4* Ct4 = (const float4*)(ws + 16384 + t * NDIM);

    // r_sym[t][j] = Sa + Bh*x[j] + Bt*x[t] + Ch*y[j] + Ct*y[t]
    f32x2 r2[32];
    #pragma unroll
    for (int q = 0; q < 16; ++q) {
        float4 sa = Sa4[q], bh = Bh4[q], bt = Bt4[q], ch = Ch4[q], ct = Ct4[q];
        float4 xq = ab0[q], yq = ub4[q];
        float e0 = fmaf(bh.x, xq.x, fmaf(bt.x, xi, fmaf(ch.x, yq.x, fmaf(ct.x, yi, sa.x))));
        float e1 = fmaf(bh.y, xq.y, fmaf(bt.y, xi, fmaf(ch.y, yq.y, fmaf(ct.y, yi, sa.y))));
        float e2 = fmaf(bh.z, xq.z, fmaf(bt.z, xi, fmaf(ch.z, yq.z, fmaf(ct.z, yi, sa.z))));
        float e3 = fmaf(bh.w, xq.w, fmaf(bt.w, xi, fmaf(ch.w, yq.w, fmaf(ct.w, yi, sa.w))));
        r2[2 * q].x = e0;     r2[2 * q].y = e1;
        r2[2 * q + 1].x = e2; r2[2 * q + 1].y = e3;
    }

    // ---- Householder tridiagonalization (pipelined) ----
    float colreg = r2[0].x;
    float dval = (t == 0) ? r2[0].x : 0.0f;
    float e2val = 0.0f;
    float akt0 = (t > 0) ? colreg : 0.0f;
    ((float*)ab0)[t] = akt0;          // publish column 0 (buffer parity k=0)
    MEMFENCE();
    float s2 = wave_sum(akt0 * akt0);
    float a1 = rl(akt0, 1);

    tri_chunk< 0,  8>(r2, colreg, s2, a1, dval, e2val, t, ab0, ab1, ub4);
    tri_chunk< 8, 16>(r2, colreg, s2, a1, dval, e2val, t, ab0, ab1, ub4);
    tri_chunk<16, 24>(r2, colreg, s2, a1, dval, e2val, t, ab0, ab1, ub4);
    tri_chunk<24, 32>(r2, colreg, s2, a1, dval, e2val, t, ab0, ab1, ub4);
    tri_chunk<32, 40>(r2, colreg, s2, a1, dval, e2val, t, ab0, ab1, ub4);
    tri_chunk<40, 48>(r2, colreg, s2, a1, dval, e2val, t, ab0, ab1, ub4);
    tri_chunk<48, 56>(r2, colreg, s2, a1, dval, e2val, t, ab0, ab1, ub4);
    tri_chunk<56, 62>(r2, colreg, s2, a1, dval, e2val, t, ab0, ab1, ub4);

    // Trailing 2x2: after k=61 the pipelined s2 = e[62]^2 already.
    e2val = (t == 62) ? s2 : e2val;
    dval = (t == 63) ? r2[31].y : dval;

    // Stash (d_t, e^2_{t-1}) pairs for the Sturm phase.
    float e2prev = __shfl_up(e2val, 1, 64);
    e2prev = (t == 0) ? 0.0f : e2prev;
    float2 dp; dp.x = dval; dp.y = e2prev;
    des[t] = dp;
    MEMFENCE();

    // Gershgorin bounds
    float eabs = sqrtf(e2val);
    float eprev = __shfl_up(eabs, 1, 64);
    eprev = (t == 0) ? 0.0f : eprev;
    float rad = eabs + eprev;
    float lo = wave_min(dval - rad);
    float hi = wave_max(dval + rad);
    float pad = 1e-3f + 1e-5f * fmaxf(fabsf(lo), fabsf(hi));
    lo -= pad;
    hi += pad;

    int idx = idxp[0];
    idx = idx < 0 ? 0 : (idx > NDIM - 1 ? NDIM - 1 : idx);

    // 64-way multisection on the Sturm sequence.
    // 2 iters: width ~(hi-lo)/65^2 < 0.03 << 0.6175 bf16 threshold.
    #pragma unroll 1
    for (int it = 0; it < 2; ++it) {
        float wdt = (hi - lo) * (1.0f / 65.0f);
        float s = lo + wdt * (float)(t + 1);
        float2 p0 = des[0];
        float q = p0.x - s;
        q = (fabsf(q) < 1e-12f) ? -1e-12f : q;
        int cnt = (q < 0.0f) ? 1 : 0;
        #pragma unroll
        for (int i = 1; i < NDIM; ++i) {
            float2 pi = des[i];
            q = pi.x - s - pi.y * __builtin_amdgcn_rcpf(q);
            q = (fabsf(q) < 1e-12f) ? -1e-12f : q;
            cnt += (q < 0.0f) ? 1 : 0;
        }
        unsigned long long m = __ballot(cnt <= idx);
        int p = (int)__popcll(m);
        float nlo = lo + wdt * (float)p;
        float nhi = lo + wdt * (float)(p + 1);
        lo = nlo;
        hi = (p >= 64) ? hi : nhi;
    }

    if (t == 0) out[b] = 0.5f * (lo + hi);
}

extern "C" void kernel_launch(void* const* d_in, const int* in_sizes, int n_in,
                              void* d_out, int out_size, void* d_ws, size_t ws_size,
                              hipStream_t stream) {
    const float* x = (const float*)d_in[0];
    const float* y = (const float*)d_in[1];
    const float* A = (const float*)d_in[2];
    const float* B = (const float*)d_in[3];
    const float* C = (const float*)d_in[4];
    const int* idxp = (const int*)d_in[5];
    float* out = (float*)d_out;
    float* ws = (float*)d_ws;
    int batch = in_sizes[0] / NDIM;

    hipLaunchKernelGGL(prep_kernel, dim3(1), dim3(64), 0, stream, A, B, C, ws);
    hipLaunchKernelGGL(bispec_eig_kernel, dim3(batch), dim3(64), 0, stream,
                       x, y, ws, idxp, out, batch);
}

// Round 12
// 908.906 us; speedup vs baseline: 1.0226x; 1.0226x over previous
//
#include <hip/hip_runtime.h>
#include <math.h>

#define NDIM 64
typedef float f32x2 __attribute__((ext_vector_type(2)));

// Broadcast lane `lane`'s value to all lanes (uniform / SGPR).
__device__ __forceinline__ float rl(float v, int lane) {
    return __uint_as_float((unsigned)__builtin_amdgcn_readlane(__float_as_uint(v), lane));
}

// DPP add step with compile-time control/row mask.
template<int CTRL, int ROW_MASK>
__device__ __forceinline__ float dpp_add(float x) {
    int m = __builtin_amdgcn_update_dpp(0, __float_as_int(x), CTRL, ROW_MASK, 0xf, true);
    return x + __int_as_float(m);
}
// Full-wave64 sum via DPP; total lands in lane 63, broadcast via readlane.
__device__ __forceinline__ float wave_sum(float x) {
    x = dpp_add<0x111, 0xf>(x);   // row_shr:1
    x = dpp_add<0x112, 0xf>(x);   // row_shr:2
    x = dpp_add<0x114, 0xf>(x);   // row_shr:4
    x = dpp_add<0x118, 0xf>(x);   // row_shr:8
    x = dpp_add<0x142, 0xa>(x);   // row_bcast:15 -> rows 1,3
    x = dpp_add<0x143, 0xc>(x);   // row_bcast:31 -> row 3
    return rl(x, 63);
}
__device__ __forceinline__ float wave_min(float v) {
    #pragma unroll
    for (int off = 1; off < 64; off <<= 1) v = fminf(v, __shfl_xor(v, off, 64));
    return v;
}
__device__ __forceinline__ float wave_max(float v) {
    #pragma unroll
    for (int off = 1; off < 64; off <<= 1) v = fmaxf(v, __shfl_xor(v, off, 64));
    return v;
}

// Householder iterations k in [K0, K1); K0 even, multiple of 8. Columns <= K0
// inert (a[j]=0 mask). Pure-VALU: all broadcasts via readlane, a-broadcast
// pairs cached in registers (av) between the matvec and the update. Update in
// p1/p2 form: r[j] -= p1*u[j] + p2*a[j]; element k+1 fixed via closed-form
// ncol. No LDS, no barriers.
template<int K0, int K1>
__device__ __forceinline__ void tri_chunk(f32x2 (&r2)[32], float& colreg,
                                          float& dval, float& e2val, const int t) {
    #pragma unroll 1
    for (int k = K0; k < K1; ++k) {
        float akt = (t > k) ? colreg : 0.0f;
        float s2 = wave_sum(akt * akt);
        float a1 = rl(akt, k + 1);
        float sigma = sqrtf(s2);
        float alpha = (a1 >= 0.0f) ? -sigma : sigma;   // e[k]=alpha, e[k]^2=s2
        e2val = (t == k) ? s2 : e2val;
        float vt = akt - ((t == k + 1) ? alpha : 0.0f);
        float vtv = 2.0f * (s2 - alpha * a1);
        float beta = (vtv > 1e-30f) ? 2.0f * __builtin_amdgcn_rcpf(vtv) : 0.0f;

        // pre-update r_t[k+1] (static window select)
        float pre_col = colreg;
        #pragma unroll
        for (int j = K0 + 1; j <= K1; ++j)
            if (j == k + 1) pre_col = (j & 1) ? r2[j >> 1].y : r2[j >> 1].x;

        // u_t = sum_j a[j]*r_t[j] - alpha*r_t[k+1]; cache the a-broadcasts.
        f32x2 av[32];
        f32x2 acc0 = {0.0f, 0.0f}, acc1 = {0.0f, 0.0f};
        #pragma unroll
        for (int p = K0 / 2; p < 32; ++p) {
            f32x2 a;
            a.x = rl(akt, 2 * p);
            a.y = rl(akt, 2 * p + 1);
            av[p] = a;
            if (p & 1) acc1 = __builtin_elementwise_fma(r2[p], a, acc1);
            else       acc0 = __builtin_elementwise_fma(r2[p], a, acc0);
        }
        float ut = (acc0.x + acc0.y) + (acc1.x + acc1.y) - alpha * pre_col;
        float vtu = wave_sum(vt * ut);
        float c  = 0.5f * beta * beta * vtu;
        float p1 = vt * beta;
        float p2 = (t > k) ? (beta * ut - 2.0f * c * vt) : 0.0f;
        float uk1 = rl(ut, k + 1);
        float ncol = pre_col - p1 * uk1 - p2 * a1 + alpha * p2;  // exact r_t[k+1]'

        // rank-2 update: r[j] -= p1*u[j] + p2*a[j]  (a from register cache)
        f32x2 np1; np1.x = -p1; np1.y = -p1;
        f32x2 np2; np2.x = -p2; np2.y = -p2;
        #pragma unroll
        for (int p = K0 / 2; p < 32; ++p) {
            f32x2 u;
            u.x = rl(ut, 2 * p);
            u.y = rl(ut, 2 * p + 1);
            r2[p] = __builtin_elementwise_fma(np1, u,
                    __builtin_elementwise_fma(np2, av[p], r2[p]));
        }
        // exact element k+1 via the closed form
        #pragma unroll
        for (int j = K0 + 1; j <= K1; ++j) {
            if (j == k + 1) {
                if (j & 1) r2[j >> 1].y = ncol; else r2[j >> 1].x = ncol;
            }
        }
        colreg = ncol;
        dval = (t == k + 1) ? ncol : dval;             // d[k+1] final after iter k
    }
}

// One-time prep: Sa = 0.5(A+A^T), Bh = 0.5B, Bt = 0.5B^T, Ch = 0.5C, Ct = 0.5C^T.
__global__ __launch_bounds__(64)
void prep_kernel(const float* __restrict__ A, const float* __restrict__ B,
                 const float* __restrict__ C, float* __restrict__ ws) {
    const int t = threadIdx.x;
    float* Sa = ws;
    float* Bh = ws + 4096;
    float* Bt = ws + 8192;
    float* Ch = ws + 12288;
    float* Ct = ws + 16384;
    for (int j = 0; j < NDIM; ++j) {
        Sa[t * NDIM + j] = 0.5f * (A[t * NDIM + j] + A[j * NDIM + t]);
        Bh[t * NDIM + j] = 0.5f * B[t * NDIM + j];
        Bt[t * NDIM + j] = 0.5f * B[j * NDIM + t];
        Ch[t * NDIM + j] = 0.5f * C[t * NDIM + j];
        Ct[t * NDIM + j] = 0.5f * C[j * NDIM + t];
    }
}

// 256 threads = 4 independent waves = 4 matrices per block. Zero LDS.
__global__ __launch_bounds__(256, 1)
void bispec_eig_kernel(const float* __restrict__ x, const float* __restrict__ y,
                       const float* __restrict__ ws, const int* __restrict__ idxp,
                       float* __restrict__ out, int batch) {
    const int t = threadIdx.x & 63;
    const int b = blockIdx.x * 4 + (threadIdx.x >> 6);
    if (b >= batch) return;

    const float xi = x[b * NDIM + t];
    const float yi = y[b * NDIM + t];

    const float4* Sa4 = (const float4*)(ws + t * NDIM);
    const float4* Bh4 = (const float4*)(ws + 4096 + t * NDIM);
    const float4* Bt4 = (const float4*)(ws + 8192 + t * NDIM);
    const float4* Ch4 = (const float4*)(ws + 12288 + t * NDIM);
    const float4* Ct4 = (const float4*)(ws + 16384 + t * NDIM);

    // r_sym[t][j] = Sa + Bh*x[j] + Bt*x[t] + Ch*y[j] + Ct*y[t]
    f32x2 r2[32];
    #pragma unroll
    for (int q = 0; q < 16; ++q) {
        float4 sa = Sa4[q], bh = Bh4[q], bt = Bt4[q], ch = Ch4[q], ct = Ct4[q];
        float x0 = rl(xi, 4 * q),     y0 = rl(yi, 4 * q);
        float x1 = rl(xi, 4 * q + 1), y1 = rl(yi, 4 * q + 1);
        float x2 = rl(xi, 4 * q + 2), y2 = rl(yi, 4 * q + 2);
        float x3 = rl(xi, 4 * q + 3), y3 = rl(yi, 4 * q + 3);
        float e0 = fmaf(bh.x, x0, fmaf(bt.x, xi, fmaf(ch.x, y0, fmaf(ct.x, yi, sa.x))));
        float e1 = fmaf(bh.y, x1, fmaf(bt.y, xi, fmaf(ch.y, y1, fmaf(ct.y, yi, sa.y))));
        float e2 = fmaf(bh.z, x2, fmaf(bt.z, xi, fmaf(ch.z, y2, fmaf(ct.z, yi, sa.z))));
        float e3 = fmaf(bh.w, x3, fmaf(bt.w, xi, fmaf(ch.w, y3, fmaf(ct.w, yi, sa.w))));
        r2[2 * q].x = e0;     r2[2 * q].y = e1;
        r2[2 * q + 1].x = e2; r2[2 * q + 1].y = e3;
    }

    // ---- Householder tridiagonalization (register-only) ----
    float colreg = r2[0].x;
    float dval = (t == 0) ? r2[0].x : 0.0f;
    float e2val = 0.0f;
    tri_chunk< 0,  8>(r2, colreg, dval, e2val, t);
    tri_chunk< 8, 16>(r2, colreg, dval, e2val, t);
    tri_chunk<16, 24>(r2, colreg, dval, e2val, t);
    tri_chunk<24, 32>(r2, colreg, dval, e2val, t);
    tri_chunk<32, 40>(r2, colreg, dval, e2val, t);
    tri_chunk<40, 48>(r2, colreg, dval, e2val, t);
    tri_chunk<48, 56>(r2, colreg, dval, e2val, t);
    tri_chunk<56, 62>(r2, colreg, dval, e2val, t);

    // Trailing 2x2: e[62] = lane63's colreg; d[63] = r[63].
    float e62 = rl(colreg, 63);
    e2val = (t == 62) ? e62 * e62 : e2val;
    dval = (t == 63) ? r2[31].y : dval;

    // Gershgorin bounds
    float eabs = sqrtf(e2val);
    float eprev = __shfl_up(eabs, 1, 64);
    eprev = (t == 0) ? 0.0f : eprev;
    float rad = eabs + eprev;
    float lo = wave_min(dval - rad);
    float hi = wave_max(dval + rad);
    float pad = 1e-3f + 1e-5f * fmaxf(fabsf(lo), fabsf(hi));
    lo -= pad;
    hi += pad;

    int idx = idxp[0];
    idx = idx < 0 ? 0 : (idx > NDIM - 1 ? NDIM - 1 : idx);

    // 64-way multisection on the Sturm sequence (2 iters: width < 0.03)
    #pragma unroll 1
    for (int it = 0; it < 2; ++it) {
        float wdt = (hi - lo) * (1.0f / 65.0f);
        float s = lo + wdt * (float)(t + 1);
        float q = rl(dval, 0) - s;
        q = (fabsf(q) < 1e-12f) ? -1e-12f : q;
        int cnt = (q < 0.0f) ? 1 : 0;
        #pragma unroll
        for (int i = 1; i < NDIM; ++i) {
            q = rl(dval, i) - s - rl(e2val, i - 1) * __builtin_amdgcn_rcpf(q);
            q = (fabsf(q) < 1e-12f) ? -1e-12f : q;
            cnt += (q < 0.0f) ? 1 : 0;
        }
        unsigned long long m = __ballot(cnt <= idx);
        int p = (int)__popcll(m);
        float nlo = lo + wdt * (float)p;
        float nhi = lo + wdt * (float)(p + 1);
        lo = nlo;
        hi = (p >= 64) ? hi : nhi;
    }

    if (t == 0) out[b] = 0.5f * (lo + hi);
}

extern "C" void kernel_launch(void* const* d_in, const int* in_sizes, int n_in,
                              void* d_out, int out_size, void* d_ws, size_t ws_size,
                              hipStream_t stream) {
    const float* x = (const float*)d_in[0];
    const float* y = (const float*)d_in[1];
    const float* A = (const float*)d_in[2];
    const float* B = (const float*)d_in[3];
    const float* C = (const float*)d_in[4];
    const int* idxp = (const int*)d_in[5];
    float* out = (float*)d_out;
    float* ws = (float*)d_ws;
    int batch = in_sizes[0] / NDIM;

    hipLaunchKernelGGL(prep_kernel, dim3(1), dim3(64), 0, stream, A, B, C, ws);
    hipLaunchKernelGGL(bispec_eig_kernel, dim3((batch + 3) / 4), dim3(256), 0, stream,
                       x, y, ws, idxp, out, batch);
}

// Round 13
// 471.392 us; speedup vs baseline: 1.9716x; 1.9281x over previous
//
#include <hip/hip_runtime.h>
#include <math.h>

#define NDIM 64
typedef float f32x2 __attribute__((ext_vector_type(2)));

#define MEMFENCE() asm volatile("" ::: "memory")

// Broadcast lane `lane`'s value to all lanes (uniform / SGPR).
__device__ __forceinline__ float rl(float v, int lane) {
    return __uint_as_float((unsigned)__builtin_amdgcn_readlane(__float_as_uint(v), lane));
}

// DPP add step with compile-time control/row mask.
template<int CTRL, int ROW_MASK>
__device__ __forceinline__ float dpp_add(float x) {
    int m = __builtin_amdgcn_update_dpp(0, __float_as_int(x), CTRL, ROW_MASK, 0xf, true);
    return x + __int_as_float(m);
}
// Full-wave64 sum via DPP; total lands in lane 63, broadcast via readlane.
__device__ __forceinline__ float wave_sum(float x) {
    x = dpp_add<0x111, 0xf>(x);   // row_shr:1
    x = dpp_add<0x112, 0xf>(x);   // row_shr:2
    x = dpp_add<0x114, 0xf>(x);   // row_shr:4
    x = dpp_add<0x118, 0xf>(x);   // row_shr:8
    x = dpp_add<0x142, 0xa>(x);   // row_bcast:15 -> rows 1,3
    x = dpp_add<0x143, 0xc>(x);   // row_bcast:31 -> row 3
    return rl(x, 63);
}
__device__ __forceinline__ float wave_min(float v) {
    #pragma unroll
    for (int off = 1; off < 64; off <<= 1) v = fminf(v, __shfl_xor(v, off, 64));
    return v;
}
__device__ __forceinline__ float wave_max(float v) {
    #pragma unroll
    for (int off = 1; off < 64; off <<= 1) v = fmaxf(v, __shfl_xor(v, off, 64));
    return v;
}

// Build symmetrized row t into r2 (32 x f32x2) using readlane broadcasts.
__device__ __forceinline__ void build_rows(f32x2 (&r2)[32], const float* ws,
                                           float xi, float yi, int t) {
    const float4* Sa4 = (const float4*)(ws + t * NDIM);
    const float4* Bh4 = (const float4*)(ws + 4096 + t * NDIM);
    const float4* Bt4 = (const float4*)(ws + 8192 + t * NDIM);
    const float4* Ch4 = (const float4*)(ws + 12288 + t * NDIM);
    const float4* Ct4 = (const float4*)(ws + 16384 + t * NDIM);
    #pragma unroll
    for (int q = 0; q < 16; ++q) {
        float4 sa = Sa4[q], bh = Bh4[q], bt = Bt4[q], ch = Ch4[q], ct = Ct4[q];
        float x0 = rl(xi, 4 * q),     y0 = rl(yi, 4 * q);
        float x1 = rl(xi, 4 * q + 1), y1 = rl(yi, 4 * q + 1);
        float x2 = rl(xi, 4 * q + 2), y2 = rl(yi, 4 * q + 2);
        float x3 = rl(xi, 4 * q + 3), y3 = rl(yi, 4 * q + 3);
        float e0 = fmaf(bh.x, x0, fmaf(bt.x, xi, fmaf(ch.x, y0, fmaf(ct.x, yi, sa.x))));
        float e1 = fmaf(bh.y, x1, fmaf(bt.y, xi, fmaf(ch.y, y1, fmaf(ct.y, yi, sa.y))));
        float e2 = fmaf(bh.z, x2, fmaf(bt.z, xi, fmaf(ch.z, y2, fmaf(ct.z, yi, sa.z))));
        float e3 = fmaf(bh.w, x3, fmaf(bt.w, xi, fmaf(ch.w, y3, fmaf(ct.w, yi, sa.w))));
        r2[2 * q].x = e0;     r2[2 * q].y = e1;
        r2[2 * q + 1].x = e2; r2[2 * q + 1].y = e3;
    }
}

// Shared tail: Gershgorin bounds + 64-way Sturm multisection, write out.
__device__ __forceinline__ void sturm_out(float dval, float e2val, int idx,
                                          int t, int b, float* out) {
    float eabs = sqrtf(e2val);
    float eprev = __shfl_up(eabs, 1, 64);
    eprev = (t == 0) ? 0.0f : eprev;
    float rad = eabs + eprev;
    float lo = wave_min(dval - rad);
    float hi = wave_max(dval + rad);
    float pad = 1e-3f + 1e-5f * fmaxf(fabsf(lo), fabsf(hi));
    lo -= pad;
    hi += pad;

    #pragma unroll 1
    for (int it = 0; it < 2; ++it) {
        float wdt = (hi - lo) * (1.0f / 65.0f);
        float s = lo + wdt * (float)(t + 1);
        float q = rl(dval, 0) - s;
        q = (fabsf(q) < 1e-12f) ? -1e-12f : q;
        int cnt = (q < 0.0f) ? 1 : 0;
        #pragma unroll
        for (int i = 1; i < NDIM; ++i) {
            q = rl(dval, i) - s - rl(e2val, i - 1) * __builtin_amdgcn_rcpf(q);
            q = (fabsf(q) < 1e-12f) ? -1e-12f : q;
            cnt += (q < 0.0f) ? 1 : 0;
        }
        unsigned long long m = __ballot(cnt <= idx);
        int p = (int)__popcll(m);
        float nlo = lo + wdt * (float)p;
        float nhi = lo + wdt * (float)(p + 1);
        lo = nlo;
        hi = (p >= 64) ? hi : nhi;
    }
    if (t == 0) out[b] = 0.5f * (lo + hi);
}

// One-time prep: Sa = 0.5(A+A^T), Bh = 0.5B, Bt = 0.5B^T, Ch = 0.5C, Ct = 0.5C^T.
__global__ __launch_bounds__(64)
void prep_kernel(const float* __restrict__ A, const float* __restrict__ B,
                 const float* __restrict__ C, float* __restrict__ ws) {
    const int t = threadIdx.x;
    float* Sa = ws;
    float* Bh = ws + 4096;
    float* Bt = ws + 8192;
    float* Ch = ws + 12288;
    float* Ct = ws + 16384;
    for (int j = 0; j < NDIM; ++j) {
        Sa[t * NDIM + j] = 0.5f * (A[t * NDIM + j] + A[j * NDIM + t]);
        Bh[t * NDIM + j] = 0.5f * B[t * NDIM + j];
        Bt[t * NDIM + j] = 0.5f * B[j * NDIM + t];
        Ch[t * NDIM + j] = 0.5f * C[t * NDIM + j];
        Ct[t * NDIM + j] = 0.5f * C[j * NDIM + t];
    }
}

// ===== Lanczos path: extreme indices (idx==0 or idx==63). Rows r2 are
// CONSTANT (no rank-2 update); per step one LDS-broadcast matvec + two DPP
// reductions. 64 = n steps -> full tridiagonalization; f32 extreme Ritz
// values accurate to ~eps*||A||. =====
__global__ __launch_bounds__(256, 2)
void lanczos_kernel(const float* __restrict__ x, const float* __restrict__ y,
                    const float* __restrict__ ws, const int* __restrict__ idxp,
                    float* __restrict__ out, int batch) {
    int idx = idxp[0];
    idx = idx < 0 ? 0 : (idx > NDIM - 1 ? NDIM - 1 : idx);
    if (idx != 0 && idx != NDIM - 1) return;   // interior: householder kernel

    const int t = threadIdx.x & 63;
    const int wv = threadIdx.x >> 6;
    const int b = blockIdx.x * 4 + wv;
    if (b >= batch) return;

    __shared__ float4 qbs[4][16];
    float4* qb = qbs[wv];
    float* qbp = (float*)qb;

    const float xi = x[b * NDIM + t];
    const float yi = y[b * NDIM + t];
    f32x2 r2[32];
    build_rows(r2, ws, xi, yi, t);

    // Lanczos: q0 = e_0; T diag alpha_k -> lane k, offdiag beta_{k+1}^2 -> lane k.
    float q = (t == 0) ? 1.0f : 0.0f;
    float qp = 0.0f, bprev = 0.0f;
    float dval = 0.0f, e2val = 0.0f;
    #pragma unroll 1
    for (int k = 0; k < NDIM; ++k) {
        qbp[t] = q;
        MEMFENCE();
        f32x2 acc0 = {0.0f, 0.0f}, acc1 = {0.0f, 0.0f};
        #pragma unroll
        for (int m = 0; m < 16; ++m) {
            float4 qq = qb[m];
            f32x2 q01; q01.x = qq.x; q01.y = qq.y;
            f32x2 q23; q23.x = qq.z; q23.y = qq.w;
            acc0 = __builtin_elementwise_fma(r2[2 * m],     q01, acc0);
            acc1 = __builtin_elementwise_fma(r2[2 * m + 1], q23, acc1);
        }
        float w = (acc0.x + acc0.y) + (acc1.x + acc1.y);
        w = fmaf(-bprev, qp, w);
        float alpha = wave_sum(q * w);
        w = fmaf(-alpha, q, w);
        float b2 = wave_sum(w * w);
        bool cap = (t == k);
        dval = cap ? alpha : dval;
        e2val = cap ? b2 : e2val;          // beta_{k+1}^2 = e[k]^2
        float binv = (b2 > 1e-20f) ? rsqrtf(b2) : 0.0f;
        qp = q;
        q = w * binv;
        bprev = b2 * binv;                  // sqrt(b2)
    }

    sturm_out(dval, e2val, idx, t, b, out);
}

// ===== Householder path: interior indices (exact-count Sturm needs a
// ghost-free tridiagonal). Verified R12 structure. =====
template<int K0, int K1>
__device__ __forceinline__ void tri_chunk(f32x2 (&r2)[32], float& colreg,
                                          float& dval, float& e2val, const int t) {
    #pragma unroll 1
    for (int k = K0; k < K1; ++k) {
        float akt = (t > k) ? colreg : 0.0f;
        float s2 = wave_sum(akt * akt);
        float a1 = rl(akt, k + 1);
        float sigma = sqrtf(s2);
        float alpha = (a1 >= 0.0f) ? -sigma : sigma;
        e2val = (t == k) ? s2 : e2val;
        float vt = akt - ((t == k + 1) ? alpha : 0.0f);
        float vtv = 2.0f * (s2 - alpha * a1);
        float beta = (vtv > 1e-30f) ? 2.0f * __builtin_amdgcn_rcpf(vtv) : 0.0f;

        float pre_col = colreg;
        #pragma unroll
        for (int j = K0 + 1; j <= K1; ++j)
            if (j == k + 1) pre_col = (j & 1) ? r2[j >> 1].y : r2[j >> 1].x;

        f32x2 acc0 = {0.0f, 0.0f}, acc1 = {0.0f, 0.0f};
        #pragma unroll
        for (int p = K0 / 2; p < 32; ++p) {
            f32x2 a;
            a.x = rl(akt, 2 * p);
            a.y = rl(akt, 2 * p + 1);
            if (p & 1) acc1 = __builtin_elementwise_fma(r2[p], a, acc1);
            else       acc0 = __builtin_elementwise_fma(r2[p], a, acc0);
        }
        float ut = (acc0.x + acc0.y) + (acc1.x + acc1.y) - alpha * pre_col;
        float vtu = wave_sum(vt * ut);
        float c  = 0.5f * beta * beta * vtu;
        float p1 = vt * beta;
        float p2 = (t > k) ? (beta * ut - 2.0f * c * vt) : 0.0f;
        float uk1 = rl(ut, k + 1);
        float ncol = pre_col - p1 * uk1 - p2 * a1 + alpha * p2;

        f32x2 np1; np1.x = -p1; np1.y = -p1;
        f32x2 np2; np2.x = -p2; np2.y = -p2;
        #pragma unroll
        for (int p = K0 / 2; p < 32; ++p) {
            f32x2 u, a;
            u.x = rl(ut, 2 * p);
            u.y = rl(ut, 2 * p + 1);
            a.x = rl(akt, 2 * p);
            a.y = rl(akt, 2 * p + 1);
            r2[p] = __builtin_elementwise_fma(np1, u,
                    __builtin_elementwise_fma(np2, a, r2[p]));
        }
        #pragma unroll
        for (int j = K0 + 1; j <= K1; ++j) {
            if (j == k + 1) {
                if (j & 1) r2[j >> 1].y = ncol; else r2[j >> 1].x = ncol;
            }
        }
        colreg = ncol;
        dval = (t == k + 1) ? ncol : dval;
    }
}

__global__ __launch_bounds__(256, 1)
void householder_kernel(const float* __restrict__ x, const float* __restrict__ y,
                        const float* __restrict__ ws, const int* __restrict__ idxp,
                        float* __restrict__ out, int batch) {
    int idx = idxp[0];
    idx = idx < 0 ? 0 : (idx > NDIM - 1 ? NDIM - 1 : idx);
    if (idx == 0 || idx == NDIM - 1) return;   // handled by lanczos kernel

    const int t = threadIdx.x & 63;
    const int b = blockIdx.x * 4 + (threadIdx.x >> 6);
    if (b >= batch) return;

    const float xi = x[b * NDIM + t];
    const float yi = y[b * NDIM + t];
    f32x2 r2[32];
    build_rows(r2, ws, xi, yi, t);

    float colreg = r2[0].x;
    float dval = (t == 0) ? r2[0].x : 0.0f;
    float e2val = 0.0f;
    tri_chunk< 0,  8>(r2, colreg, dval, e2val, t);
    tri_chunk< 8, 16>(r2, colreg, dval, e2val, t);
    tri_chunk<16, 24>(r2, colreg, dval, e2val, t);
    tri_chunk<24, 32>(r2, colreg, dval, e2val, t);
    tri_chunk<32, 40>(r2, colreg, dval, e2val, t);
    tri_chunk<40, 48>(r2, colreg, dval, e2val, t);
    tri_chunk<48, 56>(r2, colreg, dval, e2val, t);
    tri_chunk<56, 62>(r2, colreg, dval, e2val, t);

    float e62 = rl(colreg, 63);
    e2val = (t == 62) ? e62 * e62 : e2val;
    dval = (t == 63) ? r2[31].y : dval;

    sturm_out(dval, e2val, idx, t, b, out);
}

extern "C" void kernel_launch(void* const* d_in, const int* in_sizes, int n_in,
                              void* d_out, int out_size, void* d_ws, size_t ws_size,
                              hipStream_t stream) {
    const float* x = (const float*)d_in[0];
    const float* y = (const float*)d_in[1];
    const float* A = (const float*)d_in[2];
    const float* B = (const float*)d_in[3];
    const float* C = (const float*)d_in[4];
    const int* idxp = (const int*)d_in[5];
    float* out = (float*)d_out;
    float* ws = (float*)d_ws;
    int batch = in_sizes[0] / NDIM;

    hipLaunchKernelGGL(prep_kernel, dim3(1), dim3(64), 0, stream, A, B, C, ws);
    hipLaunchKernelGGL(lanczos_kernel, dim3((batch + 3) / 4), dim3(256), 0, stream,
                       x, y, ws, idxp, out, batch);
    hipLaunchKernelGGL(householder_kernel, dim3((batch + 3) / 4), dim3(256), 0, stream,
                       x, y, ws, idxp, out, batch);
}